// Round 1
// baseline (424.438 us; speedup 1.0000x reference)
//
#include <hip/hip_runtime.h>

#define BB 8
#define TT 512
#define DD 512
#define LL 24
#define WPB 8              // waves per block
#define LPW 3              // levels per wave (24 / 8)
#define NBLK (BB * TT)     // 4096 blocks, one per (b,t)

// Ticket counter for the last-block-done pattern. Zero-initialized at module
// load; never reset — each launch adds exactly NBLK increments and NBLK is a
// power of two, so (old & (NBLK-1)) == NBLK-1 identifies the final block of
// THIS launch under stream-ordered graph replays. No memset dispatch needed.
__device__ unsigned int g_ticket = 0u;

__global__ __launch_bounds__(512, 8) void hs_fused(
    const float* __restrict__ x,
    const float* __restrict__ node_vecs,
    const int* __restrict__ paths,
    const int* __restrict__ codes,
    const int* __restrict__ mask,
    float* __restrict__ partials,   // NBLK floats in ws (poisoned; fully overwritten)
    float* __restrict__ out)
{
    const int bt   = blockIdx.x;     // 0 .. B*T-1
    const int tid  = threadIdx.x;
    const int lane = tid & 63;
    // scalarized wave index -> meta addresses provably wave-uniform -> s_load
    const int wave = __builtin_amdgcn_readfirstlane(tid >> 6);   // 0..7

    const int base = bt * LL + wave * LPW;

    // meta through the SCALAR cache (s_load): zero vector-miss-queue traffic
    int msk[LPW], cod[LPW], pth[LPW];
    #pragma unroll
    for (int j = 0; j < LPW; ++j) {
        msk[j] = mask[base + j];
        cod[j] = codes[base + j];
        pth[j] = paths[base + j];
    }

    // x row direct from global: L1-resident, shared by the block's 8 waves
    const float4* xg = (const float4*)(x + (size_t)bt * DD);
    const float4 b0 = xg[lane];
    const float4 b1 = xg[lane + 64];

    // gathers: wave-uniform branch (s_cbranch) skips masked rows entirely —
    // no dummy row-0 loads occupying the TA pipe / miss queue
    float4 a0[LPW], a1[LPW];
    #pragma unroll
    for (int j = 0; j < LPW; ++j) {
        if (msk[j]) {
            const float4* nv = (const float4*)(node_vecs + (size_t)pth[j] * DD);
            a0[j] = nv[lane];
            a1[j] = nv[lane + 64];
        } else {
            a0[j] = make_float4(0.f, 0.f, 0.f, 0.f);
            a1[j] = make_float4(0.f, 0.f, 0.f, 0.f);
        }
    }

    float dot[LPW];
    #pragma unroll
    for (int j = 0; j < LPW; ++j) {
        dot[j] = a0[j].x * b0.x + a0[j].y * b0.y + a0[j].z * b0.z + a0[j].w * b0.w
               + a1[j].x * b1.x + a1[j].y * b1.y + a1[j].z * b1.z + a1[j].w * b1.w;
    }

    // 3 independent butterfly chains, interleaved (6 steps total depth)
    #pragma unroll
    for (int off = 32; off >= 1; off >>= 1) {
        #pragma unroll
        for (int j = 0; j < LPW; ++j)
            dot[j] += __shfl_xor(dot[j], off, 64);
    }

    float local = 0.0f;
    #pragma unroll
    for (int j = 0; j < LPW; ++j) {
        // z = (2c-1)*dot ; nll = softplus(z), HW transcendentals
        const float z   = cod[j] ? dot[j] : -dot[j];
        const float e   = __expf(-fabsf(z));                  // v_exp_f32
        const float nll = fmaxf(z, 0.0f) + __logf(1.0f + e);  // v_log_f32
        local += msk[j] ? nll : 0.0f;
    }

    // ---- block-level combine: 8 wave sums -> 1 float ----
    __shared__ float wsum[WPB];
    __shared__ int   s_last;
    if (lane == 0) wsum[wave] = local;
    __syncthreads();

    if (tid == 0) {
        float bsum = 0.0f;
        #pragma unroll
        for (int i = 0; i < WPB; ++i) bsum += wsum[i];
        // agent-scope release: partial visible device-wide before the ticket
        __hip_atomic_store(&partials[bt], bsum,
                           __ATOMIC_RELEASE, __HIP_MEMORY_SCOPE_AGENT);
        const unsigned int old =
            __hip_atomic_fetch_add(&g_ticket, 1u,
                                   __ATOMIC_ACQ_REL, __HIP_MEMORY_SCOPE_AGENT);
        s_last = ((old & (unsigned)(NBLK - 1)) == (unsigned)(NBLK - 1)) ? 1 : 0;
    }
    __syncthreads();
    if (!s_last) return;

    // ---- last block: deterministic fixed-order final reduction ----
    float s = 0.0f;
    #pragma unroll
    for (int r = 0; r < 8; ++r) {
        // relaxed agent-scope loads bypass possibly-stale L1/L2 (cross-XCD)
        s += __hip_atomic_load(&partials[tid + r * 512],
                               __ATOMIC_RELAXED, __HIP_MEMORY_SCOPE_AGENT);
    }

    #pragma unroll
    for (int off = 32; off >= 1; off >>= 1)
        s += __shfl_xor(s, off, 64);

    __syncthreads();                 // wsum reuse barrier
    if (lane == 0) wsum[wave] = s;
    __syncthreads();
    if (tid == 0) {
        float t = 0.0f;
        #pragma unroll
        for (int i = 0; i < WPB; ++i) t += wsum[i];
        out[0] = t * (1.0f / (float)BB);
    }
}

extern "C" void kernel_launch(void* const* d_in, const int* in_sizes, int n_in,
                              void* d_out, int out_size, void* d_ws, size_t ws_size,
                              hipStream_t stream) {
    const float* x         = (const float*)d_in[0];
    const float* node_vecs = (const float*)d_in[1];
    const int*   paths     = (const int*)d_in[2];
    const int*   codes     = (const int*)d_in[3];
    const int*   mask      = (const int*)d_in[4];
    float*       out       = (float*)d_out;
    float*       partials  = (float*)d_ws;   // 4096 floats = 16 KB, all written each launch

    hs_fused<<<NBLK, 512, 0, stream>>>(x, node_vecs, paths, codes, mask, partials, out);
}

// Round 2
// 157.720 us; speedup vs baseline: 2.6911x; 2.6911x over previous
//
#include <hip/hip_runtime.h>

#define BB 8
#define TT 512
#define DD 512
#define LL 24
#define WPB 8              // waves per block
#define LPW 3              // levels per wave (24 / 8)
#define NBLK (BB * TT)     // 4096 blocks, one per (b,t)

__global__ __launch_bounds__(512, 8) void hs_kernel(
    const float* __restrict__ x,
    const float* __restrict__ node_vecs,
    const int* __restrict__ paths,
    const int* __restrict__ codes,
    const int* __restrict__ mask,
    float* __restrict__ partials)    // NBLK floats = 16 KB
{
    const int bt   = blockIdx.x;     // 0 .. B*T-1
    const int tid  = threadIdx.x;
    const int lane = tid & 63;
    // scalarized wave index -> meta addresses provably wave-uniform -> s_load
    const int wave = __builtin_amdgcn_readfirstlane(tid >> 6);   // 0..7

    const int base = bt * LL + wave * LPW;

    // meta through the SCALAR cache (s_load): zero vector-miss-queue traffic
    int msk[LPW], cod[LPW], pth[LPW];
    #pragma unroll
    for (int j = 0; j < LPW; ++j) {
        msk[j] = mask[base + j];
        cod[j] = codes[base + j];
        pth[j] = paths[base + j];
    }

    // x row direct from global: L1-resident, shared by the block's 8 waves
    const float4* xg = (const float4*)(x + (size_t)bt * DD);
    const float4 b0 = xg[lane];
    const float4 b1 = xg[lane + 64];

    // gathers: wave-uniform branch (s_cbranch) skips masked rows entirely —
    // no dummy row-0 loads occupying the TA pipe / miss queue
    float4 a0[LPW], a1[LPW];
    #pragma unroll
    for (int j = 0; j < LPW; ++j) {
        if (msk[j]) {
            const float4* nv = (const float4*)(node_vecs + (size_t)pth[j] * DD);
            a0[j] = nv[lane];
            a1[j] = nv[lane + 64];
        } else {
            a0[j] = make_float4(0.f, 0.f, 0.f, 0.f);
            a1[j] = make_float4(0.f, 0.f, 0.f, 0.f);
        }
    }

    float dot[LPW];
    #pragma unroll
    for (int j = 0; j < LPW; ++j) {
        dot[j] = a0[j].x * b0.x + a0[j].y * b0.y + a0[j].z * b0.z + a0[j].w * b0.w
               + a1[j].x * b1.x + a1[j].y * b1.y + a1[j].z * b1.z + a1[j].w * b1.w;
    }

    // 3 independent butterfly chains, interleaved (6 steps total depth)
    #pragma unroll
    for (int off = 32; off >= 1; off >>= 1) {
        #pragma unroll
        for (int j = 0; j < LPW; ++j)
            dot[j] += __shfl_xor(dot[j], off, 64);
    }

    float local = 0.0f;
    #pragma unroll
    for (int j = 0; j < LPW; ++j) {
        // z = (2c-1)*dot ; nll = softplus(z), HW transcendentals
        const float z   = cod[j] ? dot[j] : -dot[j];
        const float e   = __expf(-fabsf(z));                  // v_exp_f32
        const float nll = fmaxf(z, 0.0f) + __logf(1.0f + e);  // v_log_f32
        local += msk[j] ? nll : 0.0f;
    }

    // block-level combine: 8 wave sums -> 1 float. NO global ticket/atomic —
    // 4096 same-address agent-scope RMWs serialize at ~76 ns each (+150 µs,
    // measured round 1). Plain store; separate tiny reduce dispatch instead.
    __shared__ float wsum[WPB];
    if (lane == 0) wsum[wave] = local;
    __syncthreads();
    if (tid == 0) {
        float bsum = 0.0f;
        #pragma unroll
        for (int i = 0; i < WPB; ++i) bsum += wsum[i];
        partials[bt] = bsum;
    }
}

__global__ __launch_bounds__(1024) void hs_reduce(
    const float* __restrict__ partials, float* __restrict__ out)
{
    const int tid  = threadIdx.x;
    const int lane = tid & 63;
    const int wave = tid >> 6;          // 0..15
    __shared__ float wsum[16];

    // 4096 floats = 1024 float4s: one vector load per thread, one latency round
    const float4 v = ((const float4*)partials)[tid];
    float s = (v.x + v.y) + (v.z + v.w);

    #pragma unroll
    for (int off = 32; off >= 1; off >>= 1)
        s += __shfl_xor(s, off, 64);

    if (lane == 0) wsum[wave] = s;
    __syncthreads();
    if (tid == 0) {
        float t = 0.0f;
        #pragma unroll
        for (int i = 0; i < 16; ++i) t += wsum[i];
        out[0] = t * (1.0f / (float)BB);
    }
}

extern "C" void kernel_launch(void* const* d_in, const int* in_sizes, int n_in,
                              void* d_out, int out_size, void* d_ws, size_t ws_size,
                              hipStream_t stream) {
    const float* x         = (const float*)d_in[0];
    const float* node_vecs = (const float*)d_in[1];
    const int*   paths     = (const int*)d_in[2];
    const int*   codes     = (const int*)d_in[3];
    const int*   mask      = (const int*)d_in[4];
    float*       out       = (float*)d_out;
    float*       partials  = (float*)d_ws;   // 4096 floats = 16 KB, all written each launch

    hs_kernel<<<NBLK, 512, 0, stream>>>(x, node_vecs, paths, codes, mask, partials);
    hs_reduce<<<1, 1024, 0, stream>>>(partials, out);
}